// Round 8
// baseline (94.795 us; speedup 1.0000x reference)
//
#include <hip/hip_runtime.h>

#define THREADS 1024
#define NBLK 512  // 65536 rows / 128 per block
#define BUFSZ 49152  // per pipeline buffer: A fp32 16KB + B f16 32KB

typedef _Float16 half8 __attribute__((ext_vector_type(8)));
typedef float floatx4 __attribute__((ext_vector_type(4)));

// --- Kernel 1: W [512(k)][512(n)] fp32 -> Wt [512(n)][512(k)] f16 ---
__global__ void wcvt_kernel(const float* __restrict__ W, unsigned short* __restrict__ Wt) {
  __shared__ float tile[32][33];
  const int tx = threadIdx.x, ty = threadIdx.y;
  const int nb = blockIdx.x * 32, kb = blockIdx.y * 32;
#pragma unroll
  for (int i = 0; i < 4; ++i)
    tile[ty + 8 * i][tx] = W[(size_t)(kb + ty + 8 * i) * 512 + nb + tx];
  __syncthreads();
#pragma unroll
  for (int i = 0; i < 4; ++i) {
    union { _Float16 h; unsigned short u; } v;
    v.h = (_Float16)tile[tx][ty + 8 * i];
    Wt[(size_t)(nb + ty + 8 * i) * 512 + kb + tx] = v.u;
  }
}

// --- Kernel 2: fused GEMM + surrogate-sigmoid + rowwise LayerNorm ---
// 1024 threads, 16 waves (4 wrow x 4 wcol), block tile 128 x 512, wave tile
// 32x128, acc[2][8]=64 AGPR, body <=64 VGPR -> 4 waves/SIMD (1 block/CU).
// BK=32, 16 chunks, 3-buffer pipeline (144KB LDS), 3 DMA/thread/chunk,
// counted vmcnt(6) = 2 chunks always in flight; two drain-free barriers per
// chunk (b1: stage(c) landed everywhere; b2: buf consumed -> refill safe).
// LDS per buffer: A fp32 [0,16K): 128 rows x 8 slots x 16B, phys=log^(row&7)
//                 B f16 [16K,48K): 512 rows x 4 slots x 16B,
//                 phys = log ^ (row&3) ^ ((row>>2)&3)
// Reduction scratch aliases buffer 0 after the K-loop.
__global__ __launch_bounds__(THREADS, 4) void lif_fused_kernel(
    const float* __restrict__ A, const unsigned short* __restrict__ Wt,
    const float* __restrict__ bias, const float* __restrict__ lnw,
    const float* __restrict__ lnb, float* __restrict__ out) {
  __shared__ uint4 smem4[9216];  // 147456 bytes
  unsigned char* smem = (unsigned char*)smem4;

  const int tid  = threadIdx.x;
  const int lane = tid & 63;
  const int wave = tid >> 6;   // 0..15
  const int wrow = wave >> 2;  // 0..3
  const int wcol = wave & 3;   // 0..3
  const int l15  = lane & 15;
  const int g    = lane >> 4;  // 0..3
  const int rowBase = blockIdx.x * 128;

  // Staging sources (inverse-swizzled global, linear LDS dest).
  // A: unit u=tid: row=u>>3, phys slot p=u&7 holds logical p^(row&7).
  const int arow = tid >> 3;
  const float* asrc =
      A + (size_t)(rowBase + arow) * 512 + ((tid & 7) ^ (arow & 7)) * 4;
  // B: units tid and tid+1024: row=u>>2, phys p=u&3 holds logical
  // p^(row&3)^((row>>2)&3). Row+256 has identical swizzle bits.
  const int brow = tid >> 2;
  const unsigned short* bsrc =
      Wt + (size_t)brow * 512 + ((tid & 3) ^ (brow & 3) ^ ((brow >> 2) & 3)) * 8;

  auto stage = [&](int buf, int c) {
    int offA = buf * BUFSZ + wave * 1024;
    offA = __builtin_amdgcn_readfirstlane(offA);
    __builtin_amdgcn_global_load_lds(
        (const __attribute__((address_space(1))) void*)(asrc + c * 32),
        (__attribute__((address_space(3))) void*)(smem + offA), 16, 0, 0);
    int offB = buf * BUFSZ + 16384 + wave * 1024;
    offB = __builtin_amdgcn_readfirstlane(offB);
    __builtin_amdgcn_global_load_lds(
        (const __attribute__((address_space(1))) void*)(bsrc + c * 32),
        (__attribute__((address_space(3))) void*)(smem + offB), 16, 0, 0);
    __builtin_amdgcn_global_load_lds(
        (const __attribute__((address_space(1))) void*)(bsrc + 256 * 512 + c * 32),
        (__attribute__((address_space(3))) void*)(smem + offB + 16384), 16, 0, 0);
  };

  // Fragment read offsets (all 2-way bank alias max = free).
  const int aRB = (wrow * 32 + l15) * 128;  // + m*2048 + buf*BUFSZ
  const int aO0 = (((g << 1) ^ (l15 & 7)) << 4);
  const int aO1 = aO0 ^ 16;
  const int bRB = 16384 + (wcol * 128 + l15) * 64 +
                  ((g ^ (l15 & 3) ^ ((l15 >> 2) & 3)) << 4);  // + n*1024

  floatx4 acc[2][8];
#pragma unroll
  for (int m = 0; m < 2; ++m)
#pragma unroll
    for (int n = 0; n < 8; ++n)
      acc[m][n] = (floatx4){0.f, 0.f, 0.f, 0.f};

  auto mk = [](float4 lo, float4 hi) {
    half8 t;
    t[0] = (_Float16)lo.x; t[1] = (_Float16)lo.y;
    t[2] = (_Float16)lo.z; t[3] = (_Float16)lo.w;
    t[4] = (_Float16)hi.x; t[5] = (_Float16)hi.y;
    t[6] = (_Float16)hi.z; t[7] = (_Float16)hi.w;
    return t;
  };

  // Prologue: 3 chunks in flight.
  stage(0, 0);
  stage(1, 1);
  stage(2, 2);

#pragma unroll
  for (int c = 0; c < 16; ++c) {
    // Wait for own stage(c) only; keep c+1, c+2 flying.
    if (c < 14) {
      asm volatile("s_waitcnt vmcnt(6)" ::: "memory");
    } else if (c == 14) {
      asm volatile("s_waitcnt vmcnt(3)" ::: "memory");
    } else {
      asm volatile("s_waitcnt vmcnt(0)" ::: "memory");
    }
    __builtin_amdgcn_s_barrier();  // everyone's stage(c) landed
    __builtin_amdgcn_sched_barrier(0);

    const int buf = c % 3;
    const unsigned char* ab = smem + buf * BUFSZ + aRB;
    half8 a0 = mk(*(const float4*)(ab + aO0), *(const float4*)(ab + aO1));
    half8 a1 = mk(*(const float4*)(ab + 2048 + aO0), *(const float4*)(ab + 2048 + aO1));
    const unsigned char* bb = smem + buf * BUFSZ + bRB;
    __builtin_amdgcn_s_setprio(1);
#pragma unroll
    for (int n = 0; n < 8; ++n) {
      half8 bf = *(const half8*)(bb + n * 1024);
      acc[0][n] = __builtin_amdgcn_mfma_f32_16x16x32_f16(a0, bf, acc[0][n], 0, 0, 0);
      acc[1][n] = __builtin_amdgcn_mfma_f32_16x16x32_f16(a1, bf, acc[1][n], 0, 0, 0);
    }
    __builtin_amdgcn_s_setprio(0);
    __builtin_amdgcn_sched_barrier(0);
    __builtin_amdgcn_s_barrier();  // all waves consumed buf -> refill safe
    __builtin_amdgcn_sched_barrier(0);
    if (c < 13) stage(buf, c + 3);
  }
  __syncthreads();

  // --- Epilogue: bias + surrogate spike + fused LayerNorm ---
  float bcol[8], lsc[8], lbc[8];
#pragma unroll
  for (int n = 0; n < 8; ++n) {
    const int col = wcol * 128 + n * 16 + l15;
    bcol[n] = bias[col];
    lsc[n]  = lnw[col];
    lbc[n]  = lnb[col];
  }
#pragma unroll
  for (int m = 0; m < 2; ++m)
#pragma unroll
    for (int n = 0; n < 8; ++n)
#pragma unroll
      for (int r = 0; r < 4; ++r) {
        // alpha=exp(-50): v == current in fp32; spike = fast_sigmoid(v-0.5, 4)
        float x  = acc[m][n][r] + bcol[n] - 0.5f;
        float bx = 4.0f * x;
        acc[m][n][r] = 0.5f * bx / (1.0f + fabsf(bx)) + 0.5f;
      }

  float rs[2][4], rq[2][4];
#pragma unroll
  for (int m = 0; m < 2; ++m)
#pragma unroll
    for (int r = 0; r < 4; ++r) {
      float s = 0.f, q = 0.f;
#pragma unroll
      for (int n = 0; n < 8; ++n) {
        float v = acc[m][n][r];
        s += v;
        q += v * v;
      }
      rs[m][r] = s;
      rq[m][r] = q;
    }
#pragma unroll
  for (int d = 1; d < 16; d <<= 1) {
#pragma unroll
    for (int m = 0; m < 2; ++m)
#pragma unroll
      for (int r = 0; r < 4; ++r) {
        rs[m][r] += __shfl_xor(rs[m][r], d, 16);
        rq[m][r] += __shfl_xor(rq[m][r], d, 16);
      }
  }

  float* redS = (float*)smem4;   // [128][4]
  float* redQ = redS + 512;      // [128][4]
  float* mv   = redQ + 512;      // [128][2]
  if (l15 == 0) {
#pragma unroll
    for (int m = 0; m < 2; ++m)
#pragma unroll
      for (int r = 0; r < 4; ++r) {
        const int row = wrow * 32 + m * 16 + g * 4 + r;
        redS[row * 4 + wcol] = rs[m][r];
        redQ[row * 4 + wcol] = rq[m][r];
      }
  }
  __syncthreads();
  if (tid < 128) {
    const float S = redS[tid * 4] + redS[tid * 4 + 1] + redS[tid * 4 + 2] + redS[tid * 4 + 3];
    const float Q = redQ[tid * 4] + redQ[tid * 4 + 1] + redQ[tid * 4 + 2] + redQ[tid * 4 + 3];
    const float mean = S * (1.0f / 512.0f);
    const float var  = Q * (1.0f / 512.0f) - mean * mean;
    mv[tid * 2]     = mean;
    mv[tid * 2 + 1] = rsqrtf(var + 1e-6f);
  }
  __syncthreads();

#pragma unroll
  for (int m = 0; m < 2; ++m)
#pragma unroll
    for (int r = 0; r < 4; ++r) {
      const int row  = wrow * 32 + m * 16 + g * 4 + r;
      const float mean = mv[row * 2];
      const float rstd = mv[row * 2 + 1];
      const size_t base = (size_t)(rowBase + row) * 512;
#pragma unroll
      for (int n = 0; n < 8; ++n) {
        const int col = wcol * 128 + n * 16 + l15;
        out[base + col] = (acc[m][n][r] - mean) * rstd * lsc[n] + lbc[n];
      }
    }
}

extern "C" void kernel_launch(void* const* d_in, const int* in_sizes, int n_in,
                              void* d_out, int out_size, void* d_ws, size_t ws_size,
                              hipStream_t stream) {
  const float* spikes = (const float*)d_in[0];
  const float* W      = (const float*)d_in[1];
  const float* b      = (const float*)d_in[2];
  const float* lnw    = (const float*)d_in[3];
  const float* lnb    = (const float*)d_in[4];
  float* out = (float*)d_out;
  unsigned short* Wt = (unsigned short*)d_ws;  // 512*512*2 = 512 KB scratch

  wcvt_kernel<<<dim3(16, 16), dim3(32, 8), 0, stream>>>(W, Wt);
  lif_fused_kernel<<<NBLK, THREADS, 0, stream>>>(spikes, Wt, b, lnw, lnb, out);
}

// Round 9
// 89.577 us; speedup vs baseline: 1.0583x; 1.0583x over previous
//
#include <hip/hip_runtime.h>

#define THREADS 512
#define NBLK 512     // 65536 rows / 128 per block
#define BUFSZ 49152  // per buffer: A fp32 16KB + B f16 32KB
#define BOFF 16384

typedef _Float16 half8 __attribute__((ext_vector_type(8)));
typedef float floatx4 __attribute__((ext_vector_type(4)));

// --- Kernel 1: W [512(k)][512(n)] fp32 -> Wt [512(n)][512(k)] f16 ---
__global__ void wcvt_kernel(const float* __restrict__ W, unsigned short* __restrict__ Wt) {
  __shared__ float tile[32][33];
  const int tx = threadIdx.x, ty = threadIdx.y;
  const int nb = blockIdx.x * 32, kb = blockIdx.y * 32;
#pragma unroll
  for (int i = 0; i < 4; ++i)
    tile[ty + 8 * i][tx] = W[(size_t)(kb + ty + 8 * i) * 512 + nb + tx];
  __syncthreads();
#pragma unroll
  for (int i = 0; i < 4; ++i) {
    union { _Float16 h; unsigned short u; } v;
    v.h = (_Float16)tile[tx][ty + 8 * i];
    Wt[(size_t)(nb + ty + 8 * i) * 512 + kb + tx] = v.u;
  }
}

// --- Kernel 2: fused GEMM + surrogate-sigmoid + rowwise LayerNorm ---
// m201-style phase template. Block 128x512, 8 waves (2x4), wave tile 64x128.
// BK=32, 16 K-tiles, 4 phases/tile (C-quadrants), 3 LDS buffers (144KB),
// vmcnt(6) ONCE per tile (1 tile always in flight), stage(c+2) spread across
// phases 0-2 (3-buf rotation -> race-free while reading buf c).
// LDS buffer: A fp32 [0,16K): row r at r*128, 8 slots x16B, phys=log^(r&7)
//             B f16 [16K,48K): col n at n*64, 4 slots x16B,
//             phys = log ^ (n&3) ^ ((n>>2)&3)
__global__ __launch_bounds__(THREADS, 2) void lif_fused_kernel(
    const float* __restrict__ A, const unsigned short* __restrict__ Wt,
    const float* __restrict__ bias, const float* __restrict__ lnw,
    const float* __restrict__ lnb, float* __restrict__ out) {
  __shared__ uint4 smem4[9216];  // 147456 bytes
  unsigned char* smem = (unsigned char*)smem4;

  const int tid  = threadIdx.x;
  const int lane = tid & 63;
  const int wave = tid >> 6;   // 0..7
  const int wrow = wave >> 2;  // 0..1
  const int wcol = wave & 3;   // 0..3
  const int l15  = lane & 15;
  const int g    = lane >> 4;  // 0..3
  const int rowBase = blockIdx.x * 128;

  // Staging sources (inverse-swizzled global, linear LDS dest = tid*16).
  const int ar = tid >> 3;  // 0..63
  const float* asrc =
      A + (size_t)(rowBase + ar) * 512 + (((tid & 7) ^ (ar & 7)) << 2);
  const int sB = (tid & 3) ^ ((tid >> 2) & 3) ^ ((tid >> 4) & 3);
  const unsigned short* bsrc = Wt + (size_t)(tid >> 2) * 512 + sB * 8;

  auto stageA = [&](int buf, int c) {
    int o0 = buf * BUFSZ + wave * 1024;
    o0 = __builtin_amdgcn_readfirstlane(o0);
    __builtin_amdgcn_global_load_lds(
        (const __attribute__((address_space(1))) void*)(asrc + c * 32),
        (__attribute__((address_space(3))) void*)(smem + o0), 16, 0, 0);
    int o1 = buf * BUFSZ + 8192 + wave * 1024;
    o1 = __builtin_amdgcn_readfirstlane(o1);
    __builtin_amdgcn_global_load_lds(
        (const __attribute__((address_space(1))) void*)(asrc + 32768 + c * 32),
        (__attribute__((address_space(3))) void*)(smem + o1), 16, 0, 0);
  };
  auto stageB = [&](int buf, int c, int i0) {
#pragma unroll
    for (int i = 0; i < 2; ++i) {
      int o = buf * BUFSZ + BOFF + (i0 + i) * 8192 + wave * 1024;
      o = __builtin_amdgcn_readfirstlane(o);
      __builtin_amdgcn_global_load_lds(
          (const __attribute__((address_space(1))) void*)(bsrc + (i0 + i) * 65536 + c * 32),
          (__attribute__((address_space(3))) void*)(smem + o), 16, 0, 0);
    }
  };

  // Fragment read bases.
  const int aBase = (wrow * 64 + l15) * 128 + (((2 * g) ^ (l15 & 7)) << 4);  // +m*2048
  const int bBase = BOFF + (wcol * 128 + l15) * 64 +
                    ((g ^ (l15 & 3) ^ ((l15 >> 2) & 3)) << 4);  // + n*1024

  floatx4 acc[4][8];
#pragma unroll
  for (int m = 0; m < 4; ++m)
#pragma unroll
    for (int n = 0; n < 8; ++n)
      acc[m][n] = (floatx4){0.f, 0.f, 0.f, 0.f};

  auto mk = [](float4 lo, float4 hi) {
    half8 t;
    t[0] = (_Float16)lo.x; t[1] = (_Float16)lo.y;
    t[2] = (_Float16)lo.z; t[3] = (_Float16)lo.w;
    t[4] = (_Float16)hi.x; t[5] = (_Float16)hi.y;
    t[6] = (_Float16)hi.z; t[7] = (_Float16)hi.w;
    return t;
  };

  // Prologue: tiles 0 and 1 in flight (6 DMA each, FIFO order preserved).
  stageA(0, 0); stageB(0, 0, 0); stageB(0, 0, 2);
  stageA(1, 1); stageB(1, 1, 0); stageB(1, 1, 2);

#pragma unroll
  for (int c = 0; c < 16; ++c) {
    if (c < 15) {
      asm volatile("s_waitcnt vmcnt(6)" ::: "memory");  // stage(c) landed
    } else {
      asm volatile("s_waitcnt vmcnt(0)" ::: "memory");
    }
    __builtin_amdgcn_s_barrier();  // everyone's stage(c) landed
    __builtin_amdgcn_sched_barrier(0);

    const int buf = c % 3;
    const int nbuf = (c + 2) % 3;
    const unsigned char* base = smem + buf * BUFSZ;

    // ---- P0: quadrant (m0-1, n0-3) ----
    half8 a0, a1, b0, b1, b2, b3;
    {
      int o = aBase;
      a0 = mk(*(const float4*)(base + o), *(const float4*)(base + (o ^ 16)));
      o = aBase + 2048;
      a1 = mk(*(const float4*)(base + o), *(const float4*)(base + (o ^ 16)));
    }
    b0 = *(const half8*)(base + bBase);
    b1 = *(const half8*)(base + bBase + 1024);
    b2 = *(const half8*)(base + bBase + 2048);
    b3 = *(const half8*)(base + bBase + 3072);
    if (c < 14) stageA(nbuf, c + 2);
    __builtin_amdgcn_s_setprio(1);
    acc[0][0] = __builtin_amdgcn_mfma_f32_16x16x32_f16(a0, b0, acc[0][0], 0, 0, 0);
    acc[1][0] = __builtin_amdgcn_mfma_f32_16x16x32_f16(a1, b0, acc[1][0], 0, 0, 0);
    acc[0][1] = __builtin_amdgcn_mfma_f32_16x16x32_f16(a0, b1, acc[0][1], 0, 0, 0);
    acc[1][1] = __builtin_amdgcn_mfma_f32_16x16x32_f16(a1, b1, acc[1][1], 0, 0, 0);
    acc[0][2] = __builtin_amdgcn_mfma_f32_16x16x32_f16(a0, b2, acc[0][2], 0, 0, 0);
    acc[1][2] = __builtin_amdgcn_mfma_f32_16x16x32_f16(a1, b2, acc[1][2], 0, 0, 0);
    acc[0][3] = __builtin_amdgcn_mfma_f32_16x16x32_f16(a0, b3, acc[0][3], 0, 0, 0);
    acc[1][3] = __builtin_amdgcn_mfma_f32_16x16x32_f16(a1, b3, acc[1][3], 0, 0, 0);
    __builtin_amdgcn_s_setprio(0);
    __builtin_amdgcn_s_barrier();
    __builtin_amdgcn_sched_barrier(0);

    // ---- P1: quadrant (m0-1, n4-7) ----
    half8 b4, b5, b6, b7;
    b4 = *(const half8*)(base + bBase + 4096);
    b5 = *(const half8*)(base + bBase + 5120);
    b6 = *(const half8*)(base + bBase + 6144);
    b7 = *(const half8*)(base + bBase + 7168);
    if (c < 14) stageB(nbuf, c + 2, 0);
    __builtin_amdgcn_s_setprio(1);
    acc[0][4] = __builtin_amdgcn_mfma_f32_16x16x32_f16(a0, b4, acc[0][4], 0, 0, 0);
    acc[1][4] = __builtin_amdgcn_mfma_f32_16x16x32_f16(a1, b4, acc[1][4], 0, 0, 0);
    acc[0][5] = __builtin_amdgcn_mfma_f32_16x16x32_f16(a0, b5, acc[0][5], 0, 0, 0);
    acc[1][5] = __builtin_amdgcn_mfma_f32_16x16x32_f16(a1, b5, acc[1][5], 0, 0, 0);
    acc[0][6] = __builtin_amdgcn_mfma_f32_16x16x32_f16(a0, b6, acc[0][6], 0, 0, 0);
    acc[1][6] = __builtin_amdgcn_mfma_f32_16x16x32_f16(a1, b6, acc[1][6], 0, 0, 0);
    acc[0][7] = __builtin_amdgcn_mfma_f32_16x16x32_f16(a0, b7, acc[0][7], 0, 0, 0);
    acc[1][7] = __builtin_amdgcn_mfma_f32_16x16x32_f16(a1, b7, acc[1][7], 0, 0, 0);
    __builtin_amdgcn_s_setprio(0);
    __builtin_amdgcn_s_barrier();
    __builtin_amdgcn_sched_barrier(0);

    // ---- P2: quadrant (m2-3, n4-7) ----
    half8 a2, a3;
    {
      int o = aBase + 4096;
      a2 = mk(*(const float4*)(base + o), *(const float4*)(base + (o ^ 16)));
      o = aBase + 6144;
      a3 = mk(*(const float4*)(base + o), *(const float4*)(base + (o ^ 16)));
    }
    if (c < 14) stageB(nbuf, c + 2, 2);
    __builtin_amdgcn_s_setprio(1);
    acc[2][4] = __builtin_amdgcn_mfma_f32_16x16x32_f16(a2, b4, acc[2][4], 0, 0, 0);
    acc[3][4] = __builtin_amdgcn_mfma_f32_16x16x32_f16(a3, b4, acc[3][4], 0, 0, 0);
    acc[2][5] = __builtin_amdgcn_mfma_f32_16x16x32_f16(a2, b5, acc[2][5], 0, 0, 0);
    acc[3][5] = __builtin_amdgcn_mfma_f32_16x16x32_f16(a3, b5, acc[3][5], 0, 0, 0);
    acc[2][6] = __builtin_amdgcn_mfma_f32_16x16x32_f16(a2, b6, acc[2][6], 0, 0, 0);
    acc[3][6] = __builtin_amdgcn_mfma_f32_16x16x32_f16(a3, b6, acc[3][6], 0, 0, 0);
    acc[2][7] = __builtin_amdgcn_mfma_f32_16x16x32_f16(a2, b7, acc[2][7], 0, 0, 0);
    acc[3][7] = __builtin_amdgcn_mfma_f32_16x16x32_f16(a3, b7, acc[3][7], 0, 0, 0);
    __builtin_amdgcn_s_setprio(0);
    __builtin_amdgcn_s_barrier();
    __builtin_amdgcn_sched_barrier(0);

    // ---- P3: quadrant (m2-3, n0-3), registers only ----
    __builtin_amdgcn_s_setprio(1);
    acc[2][0] = __builtin_amdgcn_mfma_f32_16x16x32_f16(a2, b0, acc[2][0], 0, 0, 0);
    acc[3][0] = __builtin_amdgcn_mfma_f32_16x16x32_f16(a3, b0, acc[3][0], 0, 0, 0);
    acc[2][1] = __builtin_amdgcn_mfma_f32_16x16x32_f16(a2, b1, acc[2][1], 0, 0, 0);
    acc[3][1] = __builtin_amdgcn_mfma_f32_16x16x32_f16(a3, b1, acc[3][1], 0, 0, 0);
    acc[2][2] = __builtin_amdgcn_mfma_f32_16x16x32_f16(a2, b2, acc[2][2], 0, 0, 0);
    acc[3][2] = __builtin_amdgcn_mfma_f32_16x16x32_f16(a3, b2, acc[3][2], 0, 0, 0);
    acc[2][3] = __builtin_amdgcn_mfma_f32_16x16x32_f16(a2, b3, acc[2][3], 0, 0, 0);
    acc[3][3] = __builtin_amdgcn_mfma_f32_16x16x32_f16(a3, b3, acc[3][3], 0, 0, 0);
    __builtin_amdgcn_s_setprio(0);
    __builtin_amdgcn_sched_barrier(0);
  }
  __syncthreads();

  // --- Epilogue: bias + surrogate spike + fused LayerNorm ---
  float bcol[8], lsc[8], lbc[8];
#pragma unroll
  for (int n = 0; n < 8; ++n) {
    const int col = wcol * 128 + n * 16 + l15;
    bcol[n] = bias[col];
    lsc[n]  = lnw[col];
    lbc[n]  = lnb[col];
  }
#pragma unroll
  for (int m = 0; m < 4; ++m)
#pragma unroll
    for (int n = 0; n < 8; ++n)
#pragma unroll
      for (int r = 0; r < 4; ++r) {
        // alpha=exp(-50): v == current in fp32; spike = fast_sigmoid(v-0.5, 4)
        float x  = acc[m][n][r] + bcol[n] - 0.5f;
        float bx = 4.0f * x;
        acc[m][n][r] = 0.5f * bx / (1.0f + fabsf(bx)) + 0.5f;
      }

  float rs[4][4], rq[4][4];
#pragma unroll
  for (int m = 0; m < 4; ++m)
#pragma unroll
    for (int r = 0; r < 4; ++r) {
      float s = 0.f, q = 0.f;
#pragma unroll
      for (int n = 0; n < 8; ++n) {
        float v = acc[m][n][r];
        s += v;
        q += v * v;
      }
      rs[m][r] = s;
      rq[m][r] = q;
    }
#pragma unroll
  for (int d = 1; d < 16; d <<= 1) {
#pragma unroll
    for (int m = 0; m < 4; ++m)
#pragma unroll
      for (int r = 0; r < 4; ++r) {
        rs[m][r] += __shfl_xor(rs[m][r], d, 16);
        rq[m][r] += __shfl_xor(rq[m][r], d, 16);
      }
  }

  float* redS = (float*)smem4;   // [128][4]
  float* redQ = redS + 512;      // [128][4]
  float* mv   = redQ + 512;      // [128][2]
  if (l15 == 0) {
#pragma unroll
    for (int m = 0; m < 4; ++m)
#pragma unroll
      for (int r = 0; r < 4; ++r) {
        const int row = wrow * 64 + m * 16 + g * 4 + r;
        redS[row * 4 + wcol] = rs[m][r];
        redQ[row * 4 + wcol] = rq[m][r];
      }
  }
  __syncthreads();
  if (tid < 128) {
    const float S = redS[tid * 4] + redS[tid * 4 + 1] + redS[tid * 4 + 2] + redS[tid * 4 + 3];
    const float Q = redQ[tid * 4] + redQ[tid * 4 + 1] + redQ[tid * 4 + 2] + redQ[tid * 4 + 3];
    const float mean = S * (1.0f / 512.0f);
    const float var  = Q * (1.0f / 512.0f) - mean * mean;
    mv[tid * 2]     = mean;
    mv[tid * 2 + 1] = rsqrtf(var + 1e-6f);
  }
  __syncthreads();

#pragma unroll
  for (int m = 0; m < 4; ++m)
#pragma unroll
    for (int r = 0; r < 4; ++r) {
      const int row  = wrow * 64 + m * 16 + g * 4 + r;
      const float mean = mv[row * 2];
      const float rstd = mv[row * 2 + 1];
      const size_t base = (size_t)(rowBase + row) * 512;
#pragma unroll
      for (int n = 0; n < 8; ++n) {
        const int col = wcol * 128 + n * 16 + l15;
        out[base + col] = (acc[m][n][r] - mean) * rstd * lsc[n] + lbc[n];
      }
    }
}

extern "C" void kernel_launch(void* const* d_in, const int* in_sizes, int n_in,
                              void* d_out, int out_size, void* d_ws, size_t ws_size,
                              hipStream_t stream) {
  const float* spikes = (const float*)d_in[0];
  const float* W      = (const float*)d_in[1];
  const float* b      = (const float*)d_in[2];
  const float* lnw    = (const float*)d_in[3];
  const float* lnb    = (const float*)d_in[4];
  float* out = (float*)d_out;
  unsigned short* Wt = (unsigned short*)d_ws;  // 512*512*2 = 512 KB scratch

  wcvt_kernel<<<dim3(16, 16), dim3(32, 8), 0, stream>>>(W, Wt);
  lif_fused_kernel<<<NBLK, THREADS, 0, stream>>>(spikes, Wt, b, lnw, lnb, out);
}